// Round 4
// baseline (644.580 us; speedup 1.0000x reference)
//
#include <hip/hip_runtime.h>

// Problem constants (from reference)
#define N_NODES 20000
#define F_IN    512
#define D_H     256
#define E_EDGES 200000
#define L_LAYERS 3
#define T_ETYPES 2

typedef __attribute__((ext_vector_type(8))) short bf16x8;
typedef __attribute__((ext_vector_type(4))) float f32x4;

__device__ __forceinline__ unsigned short f2b(float f) {
    unsigned int u = __float_as_uint(f);
    u = (u + 0x7FFFu + ((u >> 16) & 1u)) >> 16;   // round-nearest-even
    return (unsigned short)u;
}
__device__ __forceinline__ unsigned int pack2(float a, float b) {
    return (unsigned int)f2b(a) | ((unsigned int)f2b(b) << 16);
}

// ---------------- bf16 MFMA GEMM (lin / pool) ----------------
// C[M, NOUT slice] = act(A @ W^T + bias). Block 64x128, 4 waves 2x2, wave 32x64.
// LDS fragment order: per 16x32 tile, elem (n,k) at tile*512 + ((k>>3)*16+(n&15))*8 + (k&7)
// -> every ds_read_b128 is base+lane*16, bank-uniform.
template <int A_FP32>
__global__ __launch_bounds__(256) void gemm_mfma(
    const void* __restrict__ Ap, const unsigned short* __restrict__ W,
    const float* __restrict__ bias, unsigned short* __restrict__ Cout,
    int M, int K, int ldc, int relu)
{
    __shared__ unsigned short sA[64 * 32];
    __shared__ unsigned short sB[128 * 32];
    const int tid  = threadIdx.x;
    const int lane = tid & 63;
    const int w    = tid >> 6;
    const int wm   = w >> 1, wn = w & 1;
    const int bm   = blockIdx.y * 64;
    const int bn   = blockIdx.x * 128;

    const int sma = tid >> 2, qa = tid & 3;
    const int aoff = ((sma >> 4) << 9) + ((qa * 16 + (sma & 15)) << 3);
    const int arow = min(bm + sma, M - 1);
    const int snb = tid >> 1, hb = tid & 1;
    const int boff0 = ((snb >> 4) << 9) + (((hb * 2 + 0) * 16 + (snb & 15)) << 3);
    const int boff1 = ((snb >> 4) << 9) + (((hb * 2 + 1) * 16 + (snb & 15)) << 3);
    const unsigned short* bPtr = W + (size_t)(bn + snb) * K + hb * 16;

    f32x4 acc[2][4] = {};

    for (int k0 = 0; k0 < K; k0 += 32) {
        uint4 av;
        if (A_FP32) {
            const float* aPtrF = (const float*)Ap + (size_t)arow * K + qa * 8 + k0;
            const float4 f0 = *(const float4*)(aPtrF);
            const float4 f1 = *(const float4*)(aPtrF + 4);
            av.x = pack2(f0.x, f0.y); av.y = pack2(f0.z, f0.w);
            av.z = pack2(f1.x, f1.y); av.w = pack2(f1.z, f1.w);
        } else {
            av = *(const uint4*)((const unsigned short*)Ap + (size_t)arow * K + qa * 8 + k0);
        }
        const uint4 bv0 = *(const uint4*)(bPtr + k0);
        const uint4 bv1 = *(const uint4*)(bPtr + k0 + 8);
        __syncthreads();
        *(uint4*)(sA + aoff)  = av;
        *(uint4*)(sB + boff0) = bv0;
        *(uint4*)(sB + boff1) = bv1;
        __syncthreads();
        bf16x8 af[2], bf[4];
#pragma unroll
        for (int i = 0; i < 2; ++i)
            af[i] = *(const bf16x8*)(sA + ((wm * 2 + i) << 9) + lane * 8);
#pragma unroll
        for (int j = 0; j < 4; ++j)
            bf[j] = *(const bf16x8*)(sB + ((wn * 4 + j) << 9) + lane * 8);
#pragma unroll
        for (int i = 0; i < 2; ++i)
#pragma unroll
            for (int j = 0; j < 4; ++j)
                acc[i][j] = __builtin_amdgcn_mfma_f32_16x16x32_bf16(
                    af[i], bf[j], acc[i][j], 0, 0, 0);
    }

    // C/D layout: col = lane&15, row = (lane>>4)*4 + reg
    const int cbase = bn + wn * 64 + (lane & 15);
    const int rbase = bm + wm * 32 + ((lane >> 4) << 2);
#pragma unroll
    for (int j = 0; j < 4; ++j) {
        const int col = cbase + j * 16;
        const float bj = bias[col];
#pragma unroll
        for (int i = 0; i < 2; ++i)
#pragma unroll
            for (int r = 0; r < 4; ++r) {
                const int row = rbase + i * 16 + r;
                if (row < M) {
                    float v = acc[i][j][r] + bj;
                    if (relu) v = fmaxf(v, 0.f);
                    Cout[(size_t)row * ldc + col] = f2b(v);
                }
            }
    }
}

// ---------------- dual GEMM + ReLU + LayerNorm + accumulate, fused ----------------
// rst = A0@W0^T + A1@W1^T + bias ; v = maybe_relu(rst) ; o = LN(v)*gamma+beta
// MODE 0: write fp32 partial. MODE 1: o += partial, write bf16. MODE 2: o += partial, write fp32.
// Block 64 rows x 256 cols (full row), 4 waves 2x2, wave 32x128 (acc[2][8]).
template <int MODE>
__global__ __launch_bounds__(256) void gemm_dual_ln(
    const unsigned short* __restrict__ A0, int lda0,
    const unsigned short* __restrict__ A1, int lda1,
    const unsigned short* __restrict__ W0, const unsigned short* __restrict__ W1,
    const float* __restrict__ bias, const float* __restrict__ gamma,
    const float* __restrict__ beta, const float* __restrict__ pin,
    void* __restrict__ outp, int M, int relu)
{
    __shared__ unsigned short sA[64 * 32];
    __shared__ unsigned short sB[256 * 32];
    __shared__ float sS[2][64], sQ[2][64];
    const int tid  = threadIdx.x;
    const int lane = tid & 63;
    const int w    = tid >> 6;
    const int wm   = w >> 1, wn = w & 1;
    const int bm   = blockIdx.x * 64;

    const int sma = tid >> 2, qa = tid & 3;
    const int aoff = ((sma >> 4) << 9) + ((qa * 16 + (sma & 15)) << 3);
    const int arow = min(bm + sma, M - 1);
    const int nb = tid;  // B row 0..255

    f32x4 acc[2][8] = {};

    for (int pass = 0; pass < 2; ++pass) {
        const unsigned short* __restrict__ A = pass ? A1 : A0;
        const int lda = pass ? lda1 : lda0;
        const unsigned short* __restrict__ W = pass ? W1 : W0;
        const unsigned short* aPtr = A + (size_t)arow * lda + qa * 8;
        const unsigned short* bPtr = W + (size_t)nb * D_H;
        for (int k0 = 0; k0 < D_H; k0 += 32) {
            const uint4 av = *(const uint4*)(aPtr + k0);
            uint4 bv[4];
#pragma unroll
            for (int kg = 0; kg < 4; ++kg)
                bv[kg] = *(const uint4*)(bPtr + k0 + kg * 8);
            __syncthreads();
            *(uint4*)(sA + aoff) = av;
#pragma unroll
            for (int kg = 0; kg < 4; ++kg)
                *(uint4*)(sB + ((nb >> 4) << 9) + ((kg * 16 + (nb & 15)) << 3)) = bv[kg];
            __syncthreads();
            bf16x8 af[2];
#pragma unroll
            for (int i = 0; i < 2; ++i)
                af[i] = *(const bf16x8*)(sA + ((wm * 2 + i) << 9) + lane * 8);
#pragma unroll
            for (int j = 0; j < 8; ++j) {
                const bf16x8 bf = *(const bf16x8*)(sB + ((wn * 8 + j) << 9) + lane * 8);
#pragma unroll
                for (int i = 0; i < 2; ++i)
                    acc[i][j] = __builtin_amdgcn_mfma_f32_16x16x32_bf16(
                        af[i], bf, acc[i][j], 0, 0, 0);
            }
        }
    }

    // Epilogue: per-row LN over 256 cols (split across wn=0/1 -> LDS combine).
    const int cbase = wn * 128 + (lane & 15);
    float bia[8], gam[8], bet[8];
#pragma unroll
    for (int j = 0; j < 8; ++j) {
        const int col = cbase + j * 16;
        bia[j] = bias[col]; gam[j] = gamma[col]; bet[j] = beta[col];
    }
    __syncthreads();  // sB reads done; reuse LDS for stats is separate arrays anyway
#pragma unroll
    for (int i = 0; i < 2; ++i)
#pragma unroll
        for (int r = 0; r < 4; ++r) {
            float s = 0.f, q = 0.f;
#pragma unroll
            for (int j = 0; j < 8; ++j) {
                float v = acc[i][j][r] + bia[j];
                if (relu) v = fmaxf(v, 0.f);
                s += v; q += v * v;
            }
#pragma unroll
            for (int o = 1; o < 16; o <<= 1) {
                s += __shfl_xor(s, o);
                q += __shfl_xor(q, o);
            }
            const int rl = wm * 32 + i * 16 + ((lane >> 4) << 2) + r;
            if ((lane & 15) == 0) { sS[wn][rl] = s; sQ[wn][rl] = q; }
        }
    __syncthreads();
    float mean_[2][4], inv_[2][4];
#pragma unroll
    for (int i = 0; i < 2; ++i)
#pragma unroll
        for (int r = 0; r < 4; ++r) {
            const int rl = wm * 32 + i * 16 + ((lane >> 4) << 2) + r;
            const float st = sS[0][rl] + sS[1][rl];
            const float qt = sQ[0][rl] + sQ[1][rl];
            const float mean = st * (1.f / 256.f);
            const float var = qt * (1.f / 256.f) - mean * mean;
            mean_[i][r] = mean;
            inv_[i][r] = rsqrtf(var + 1e-5f);
        }
#pragma unroll
    for (int i = 0; i < 2; ++i)
#pragma unroll
        for (int r = 0; r < 4; ++r) {
            const int rl = wm * 32 + i * 16 + ((lane >> 4) << 2) + r;
            const int row = bm + rl;
            if (row >= M) continue;
#pragma unroll
            for (int j = 0; j < 8; ++j) {
                const int col = cbase + j * 16;
                float v = acc[i][j][r] + bia[j];
                if (relu) v = fmaxf(v, 0.f);
                float o = (v - mean_[i][r]) * inv_[i][r] * gam[j] + bet[j];
                if (MODE >= 1) o += pin[(size_t)row * D_H + col];
                if (MODE == 1)
                    ((unsigned short*)outp)[(size_t)row * D_H + col] = f2b(o);
                else
                    ((float*)outp)[(size_t)row * D_H + col] = o;
            }
        }
}

// ---------------- weight fp32 -> bf16 (4 arrays, one dispatch) ----------------
__global__ __launch_bounds__(256) void f2b4_kernel(
    const float* __restrict__ s0, unsigned short* __restrict__ d0, int n0,
    const float* __restrict__ s1, unsigned short* __restrict__ d1, int n1,
    const float* __restrict__ s2, unsigned short* __restrict__ d2, int n2,
    const float* __restrict__ s3, unsigned short* __restrict__ d3, int n3)
{
    int i = blockIdx.x * 256 + threadIdx.x;
    const float* s; unsigned short* d;
    if (i < n0) { s = s0; d = d0; }
    else if ((i -= n0) < n1) { s = s1; d = d1; }
    else if ((i -= n1) < n2) { s = s2; d = d2; }
    else if ((i -= n2) < n3) { s = s3; d = d3; }
    else return;
    const float4 v = ((const float4*)s)[i];
    ((ushort4*)d)[i] = make_ushort4(f2b(v.x), f2b(v.y), f2b(v.z), f2b(v.w));
}

// ---------------- CSR build (both etypes batched; once per launch) ----------------
__global__ __launch_bounds__(256) void zero_int_kernel(int* p, int n)
{
    int i = blockIdx.x * 256 + threadIdx.x;
    if (i < n) p[i] = 0;
}

__global__ __launch_bounds__(256) void count_deg_kernel(
    const int* __restrict__ dst, int* __restrict__ cnt, int E2)
{
    int e = blockIdx.x * 256 + threadIdx.x;
    if (e < E2) {
        const int base = (e >= E_EDGES) ? N_NODES : 0;
        atomicAdd(&cnt[base + dst[e]], 1);
    }
}

// 3-phase scan over n elements
__global__ __launch_bounds__(256) void scanA_kernel(
    const int* __restrict__ cnt, int* __restrict__ incl, int* __restrict__ bsum, int n)
{
    __shared__ int tmp[256];
    const int tid = threadIdx.x;
    const int i = blockIdx.x * 256 + tid;
    const int v = (i < n) ? cnt[i] : 0;
    tmp[tid] = v;
    __syncthreads();
#pragma unroll
    for (int o = 1; o < 256; o <<= 1) {
        const int t = (tid >= o) ? tmp[tid - o] : 0;
        __syncthreads();
        tmp[tid] += t;
        __syncthreads();
    }
    if (i < n) incl[i] = tmp[tid];
    if (tid == 255) bsum[blockIdx.x] = tmp[255];
}

__global__ __launch_bounds__(256) void scanB_kernel(int* __restrict__ bsum, int nb)
{
    __shared__ int tmp[256];
    const int tid = threadIdx.x;
    const int v = (tid < nb) ? bsum[tid] : 0;
    tmp[tid] = v;
    __syncthreads();
#pragma unroll
    for (int o = 1; o < 256; o <<= 1) {
        const int t = (tid >= o) ? tmp[tid - o] : 0;
        __syncthreads();
        tmp[tid] += t;
        __syncthreads();
    }
    if (tid < nb) bsum[tid] = tmp[tid] - v;  // exclusive
}

__global__ __launch_bounds__(256) void scanC_kernel(
    const int* __restrict__ cnt, const int* __restrict__ incl,
    const int* __restrict__ bsum, int* __restrict__ off, int* __restrict__ cursor, int n)
{
    const int i = blockIdx.x * 256 + threadIdx.x;
    if (i < n) {
        const int e = incl[i] + bsum[blockIdx.x];
        off[i + 1] = e;
        cursor[i] = e - cnt[i];
    }
    if (i == 0) off[0] = 0;
}

__global__ __launch_bounds__(256) void fill_csr_kernel(
    const int* __restrict__ src, const int* __restrict__ dst,
    int* __restrict__ cursor, int* __restrict__ esrc, int E2)
{
    int e = blockIdx.x * 256 + threadIdx.x;
    if (e < E2) {
        const int base = (e >= E_EDGES) ? N_NODES : 0;
        const int pos = atomicAdd(&cursor[base + dst[e]], 1);
        esrc[pos] = src[e];
    }
}

// ---------------- segment max (bf16, both etypes): one wave per (node,t) ----------------
__device__ __forceinline__ ushort4 umax4(ushort4 a, ushort4 b)
{
    a.x = a.x > b.x ? a.x : b.x;
    a.y = a.y > b.y ? a.y : b.y;
    a.z = a.z > b.z ? a.z : b.z;
    a.w = a.w > b.w ? a.w : b.w;
    return a;
}

__global__ __launch_bounds__(256) void seg_max_kernel(
    const unsigned short* __restrict__ hp, const int* __restrict__ off,
    const int* __restrict__ esrc, unsigned short* __restrict__ neigh)
{
    const int g = blockIdx.x * 4 + (threadIdx.x >> 6);
    if (g >= 2 * N_NODES) return;
    const int t = (g >= N_NODES) ? 1 : 0;
    const int node = g - t * N_NODES;
    const int lane = threadIdx.x & 63;
    const int co = t * D_H + lane * 4;
    const int e0 = off[g], e1 = off[g + 1];
    ushort4 acc = make_ushort4(0, 0, 0, 0);
    int e = e0;
    for (; e + 4 <= e1; e += 4) {
        const int s0 = esrc[e + 0], s1 = esrc[e + 1];
        const int s2 = esrc[e + 2], s3 = esrc[e + 3];
        const ushort4 v0 = *(const ushort4*)(hp + (size_t)s0 * 512 + co);
        const ushort4 v1 = *(const ushort4*)(hp + (size_t)s1 * 512 + co);
        const ushort4 v2 = *(const ushort4*)(hp + (size_t)s2 * 512 + co);
        const ushort4 v3 = *(const ushort4*)(hp + (size_t)s3 * 512 + co);
        acc = umax4(umax4(umax4(acc, v0), umax4(v1, v2)), v3);
    }
    for (; e < e1; ++e)
        acc = umax4(acc, *(const ushort4*)(hp + (size_t)esrc[e] * 512 + co));
    *(ushort4*)(neigh + (size_t)node * 512 + co) = acc;
}

extern "C" void kernel_launch(void* const* d_in, const int* in_sizes, int n_in,
                              void* d_out, int out_size, void* d_ws, size_t ws_size,
                              hipStream_t stream)
{
    const float* x      = (const float*)d_in[0];
    const int*   src    = (const int*)d_in[1];
    const int*   dst    = (const int*)d_in[2];
    const float* Wlin   = (const float*)d_in[3];
    const float* blin   = (const float*)d_in[4];
    const float* Wpool  = (const float*)d_in[5];
    const float* bpool  = (const float*)d_in[6];
    const float* Wself  = (const float*)d_in[7];
    const float* Wneigh = (const float*)d_in[8];
    const float* bconv  = (const float*)d_in[9];
    const float* gamma  = (const float*)d_in[10];
    const float* beta   = (const float*)d_in[11];

    const size_t NB = (size_t)N_NODES * D_H;  // 5.12M
    char* p = (char*)d_ws;
    unsigned short* hp_b    = (unsigned short*)p; p += NB * 2 * T_ETYPES;  // [N,512]
    unsigned short* neigh_b = (unsigned short*)p; p += NB * 2 * T_ETYPES;  // [N,512]
    unsigned short* h_a     = (unsigned short*)p; p += NB * 2;
    unsigned short* h_b     = (unsigned short*)p; p += NB * 2;
    float*          partial = (float*)p;          p += NB * 4;
    unsigned short* wlin_b  = (unsigned short*)p; p += (size_t)D_H * F_IN * 2;
    const size_t WSZ = (size_t)L_LAYERS * T_ETYPES * D_H * D_H;
    unsigned short* wpool_b = (unsigned short*)p; p += WSZ * 2;
    unsigned short* wself_b = (unsigned short*)p; p += WSZ * 2;
    unsigned short* wneigh_b= (unsigned short*)p; p += WSZ * 2;
    int* ip = (int*)p;
    const int NT = T_ETYPES * N_NODES;  // 40000
    int* cnt    = ip; ip += NT;
    int* incl   = ip; ip += NT;
    int* off    = ip; ip += NT + 1;
    int* cursor = ip; ip += NT;
    int* esrc   = ip; ip += T_ETYPES * E_EDGES;
    int* bsum   = ip; ip += 256;

    const dim3 blk(256);
    const int E2 = T_ETYPES * E_EDGES;
    const dim3 e2grid((E2 + 255) / 256);
    const dim3 ntgrid((NT + 255) / 256);
    const int nScanBlk = (NT + 255) / 256;  // 157

    // ---- weights -> bf16 (one dispatch) ----
    {
        const int n0 = D_H * F_IN / 4, nw = (int)(WSZ / 4);
        const int tot = n0 + 3 * nw;
        f2b4_kernel<<<dim3((tot + 255) / 256), blk, 0, stream>>>(
            Wlin, wlin_b, n0, Wpool, wpool_b, nw, Wself, wself_b, nw, Wneigh, wneigh_b, nw);
    }

    // ---- CSR build, both etypes batched ----
    zero_int_kernel<<<ntgrid, blk, 0, stream>>>(cnt, NT);
    count_deg_kernel<<<e2grid, blk, 0, stream>>>(dst, cnt, E2);
    scanA_kernel<<<dim3(nScanBlk), blk, 0, stream>>>(cnt, incl, bsum, NT);
    scanB_kernel<<<dim3(1), blk, 0, stream>>>(bsum, nScanBlk);
    scanC_kernel<<<dim3(nScanBlk), blk, 0, stream>>>(cnt, incl, bsum, off, cursor, NT);
    fill_csr_kernel<<<e2grid, blk, 0, stream>>>(src, dst, cursor, esrc, E2);

    // ---- h0 = bf16(x @ Wlin^T + blin) : fp32 A fused-convert ----
    gemm_mfma<1><<<dim3(2, (N_NODES + 63) / 64), blk, 0, stream>>>(
        x, wlin_b, blin, h_a, N_NODES, F_IN, D_H, 0);

    unsigned short* h = h_a;
    unsigned short* hn = h_b;
    const dim3 pgrid(4, (N_NODES + 63) / 64);             // N=512 batched over etypes
    const dim3 sgrid((2 * N_NODES + 3) / 4);
    const dim3 dgrid((N_NODES + 63) / 64);
    for (int l = 0; l < L_LAYERS; ++l) {
        const int relu = (l < L_LAYERS - 1) ? 1 : 0;
        // hp[:, t*256:] = bf16(relu(h @ Wpool[l,t]^T + bpool[l,t])), both t in one dispatch
        gemm_mfma<0><<<pgrid, blk, 0, stream>>>(
            h, wpool_b + (size_t)l * T_ETYPES * D_H * D_H, bpool + (size_t)l * T_ETYPES * D_H,
            hp_b, N_NODES, D_H, T_ETYPES * D_H, 1);
        // neigh = segment_max per (node, t)
        seg_max_kernel<<<sgrid, blk, 0, stream>>>(hp_b, off, esrc, neigh_b);
        // per etype: fused dual GEMM + relu + LN + accumulate
        for (int t = 0; t < T_ETYPES; ++t) {
            const size_t wo = ((size_t)l * T_ETYPES + t) * D_H * D_H;
            const size_t bo = ((size_t)l * T_ETYPES + t) * D_H;
            if (t == 0) {
                gemm_dual_ln<0><<<dgrid, blk, 0, stream>>>(
                    h, D_H, neigh_b, T_ETYPES * D_H,
                    wself_b + wo, wneigh_b + wo, bconv + bo, gamma + bo, beta + bo,
                    nullptr, partial, N_NODES, relu);
            } else if (l < L_LAYERS - 1) {
                gemm_dual_ln<1><<<dgrid, blk, 0, stream>>>(
                    h, D_H, neigh_b + t * D_H, T_ETYPES * D_H,
                    wself_b + wo, wneigh_b + wo, bconv + bo, gamma + bo, beta + bo,
                    partial, hn, N_NODES, relu);
            } else {
                gemm_dual_ln<2><<<dgrid, blk, 0, stream>>>(
                    h, D_H, neigh_b + t * D_H, T_ETYPES * D_H,
                    wself_b + wo, wneigh_b + wo, bconv + bo, gamma + bo, beta + bo,
                    partial, d_out, N_NODES, relu);
            }
        }
        unsigned short* tmp = h; h = hn; hn = tmp;
    }
}